// Round 16
// baseline (7311.267 us; speedup 1.0000x reference)
//
#include <hip/hip_runtime.h>
#include <math.h>

#define NBLK 48
#define BLK  512
#define NSTATE 3072
#define HID  768
typedef unsigned long long u64;
typedef unsigned int u32;

__device__ const float d_AT[7][6] = {
  {0.f,0.f,0.f,0.f,0.f,0.f},
  {0.161f,0.f,0.f,0.f,0.f,0.f},
  {-0.008480655492356989f,0.335480655492357f,0.f,0.f,0.f,0.f},
  {2.8971530571054935f,-6.359448489975075f,4.3622954328695815f,0.f,0.f,0.f},
  {5.325864828439257f,-11.748883564062828f,7.4955393428898365f,-0.09249506636175525f,0.f,0.f},
  {5.86145544294642f,-12.92096931784711f,8.159367898576159f,-0.071584973281401f,-0.028269050394068383f,0.f},
  {0.09646076681806523f,0.01f,0.4798896504144996f,1.379008574103742f,-3.290069515436081f,2.324710524099774f},
};
__device__ const float d_EC[7] = {
  -0.001780011052226f,-0.000816434459657f,0.007880878010262f,-0.144711007173263f,
   0.582357165452555f,-0.458082105929187f,0.015151515151515152f };

namespace {
constexpr float SBc = 0.09646076681806523f+0.01f+0.4798896504144996f
                    +1.379008574103742f+(-3.290069515436081f)+2.324710524099774f;
constexpr float SEc = -0.001780011052226f-0.000816434459657f+0.007880878010262f
                      -0.144711007173263f+0.582357165452555f-0.458082105929187f
                      +0.015151515151515152f;
}

// Cross-block state: {tag:hi32, value:lo32} words, ping-pong buffered.
struct GT { u64 h[2][HID]; u64 p[2][NBLK]; };
__device__ GT gt;
__device__ int g_abort;
// Precomputed M = W_in @ W_out (768x768) and c0 = W_in @ b_out (768)
__device__ __align__(16) float g_M[HID*HID];
__device__ float g_c0[HID];

__global__ void reset_kernel(){
  u64* w = reinterpret_cast<u64*>(&gt);
  const int n = (int)(sizeof(GT)/8);
  for (int i = blockIdx.x*blockDim.x + threadIdx.x; i < n; i += gridDim.x*blockDim.x)
    __hip_atomic_store(w + i, 0ull, __ATOMIC_RELAXED, __HIP_MEMORY_SCOPE_AGENT);
  if (blockIdx.x == 0 && threadIdx.x == 0)
    __hip_atomic_store(&g_abort, 0, __ATOMIC_RELAXED, __HIP_MEMORY_SCOPE_AGENT);
}

// prep: 96 blocks x 8 rows. Win rows staged in 96KB dynamic LDS (broadcast reads);
// Wout read exactly ONCE per block (coalesced); 8 k-segments reduced via LDS.
__global__ __launch_bounds__(512, 1)
void prep_kernel(const float* __restrict__ Win, const float* __restrict__ Wout,
                 const float* __restrict__ bout){
  extern __shared__ float wl[];                 // 8*3072 floats; head reused as reduce buf
  const int blk = blockIdx.x;
  const int t = threadIdx.x;
  {
    const float4* wsrc = reinterpret_cast<const float4*>(Win + (size_t)blk*8*NSTATE);
    float4* wdst = reinterpret_cast<float4*>(wl);
    for (int i = t; i < 8*NSTATE/4; i += 512) wdst[i] = wsrc[i];
  }
  __syncthreads();
  const int seg = t >> 6;                       // wave index = k-segment (broadcast-friendly)
  const int cb  = (t & 63) * 12;
  float acc[8][12];
  #pragma unroll
  for (int r = 0; r < 8; ++r)
    #pragma unroll
    for (int j = 0; j < 12; ++j) acc[r][j] = 0.f;
  const int k0 = seg * 384;
  for (int k = 0; k < 384; ++k){
    const float4* wo4 = reinterpret_cast<const float4*>(Wout + (size_t)(k0 + k)*HID + cb);
    const float4 a0 = wo4[0], a1 = wo4[1], a2 = wo4[2];
    #pragma unroll
    for (int r = 0; r < 8; ++r){
      const float wv = wl[r*NSTATE + k0 + k];   // same addr across wave -> LDS broadcast
      acc[r][0]=fmaf(wv,a0.x,acc[r][0]); acc[r][1]=fmaf(wv,a0.y,acc[r][1]);
      acc[r][2]=fmaf(wv,a0.z,acc[r][2]); acc[r][3]=fmaf(wv,a0.w,acc[r][3]);
      acc[r][4]=fmaf(wv,a1.x,acc[r][4]); acc[r][5]=fmaf(wv,a1.y,acc[r][5]);
      acc[r][6]=fmaf(wv,a1.z,acc[r][6]); acc[r][7]=fmaf(wv,a1.w,acc[r][7]);
      acc[r][8]=fmaf(wv,a2.x,acc[r][8]); acc[r][9]=fmaf(wv,a2.y,acc[r][9]);
      acc[r][10]=fmaf(wv,a2.z,acc[r][10]); acc[r][11]=fmaf(wv,a2.w,acc[r][11]);
    }
  }
  __syncthreads();                              // Win staging no longer needed
  for (int r = 0; r < 8; ++r){
    #pragma unroll
    for (int j = 0; j < 12; ++j) wl[seg*HID + cb + j] = acc[r][j];
    __syncthreads();
    for (int c = t; c < HID; c += 512){
      float s2 = 0.f;
      #pragma unroll
      for (int s3 = 0; s3 < 8; ++s3) s2 += wl[s3*HID + c];
      g_M[(size_t)(blk*8 + r)*HID + c] = s2;
    }
    __syncthreads();
  }
  // c0 rows (Win L2-hot now)
  {
    const int rl = t >> 6, lane = t & 63;
    const int r = blk*8 + rl;
    const float4* wr = reinterpret_cast<const float4*>(Win + (size_t)r*NSTATE) + lane;
    const float4* bo = reinterpret_cast<const float4*>(bout) + lane;
    float a2c = 0.f;
    #pragma unroll
    for (int i = 0; i < 12; ++i){
      float4 w = wr[64*i], b = bo[64*i];
      a2c = fmaf(w.x,b.x, fmaf(w.y,b.y, fmaf(w.z,b.z, fmaf(w.w,b.w, a2c))));
    }
    a2c += __shfl_xor(a2c,32); a2c += __shfl_xor(a2c,16); a2c += __shfl_xor(a2c,8);
    a2c += __shfl_xor(a2c,4);  a2c += __shfl_xor(a2c,2);  a2c += __shfl_xor(a2c,1);
    if (lane == 0) g_c0[r] = a2c;
  }
}

__device__ __forceinline__ int abort_now(){
  return __hip_atomic_load(&g_abort, __ATOMIC_RELAXED, __HIP_MEMORY_SCOPE_AGENT);
}
__device__ __forceinline__ void raise_abort(){
  __hip_atomic_store(&g_abort, 1, __ATOMIC_RELAXED, __HIP_MEMORY_SCOPE_AGENT);
}
__device__ __forceinline__ void stT(u64* p, u32 tag, float v){
  u32 b; __builtin_memcpy(&b, &v, 4);
  __hip_atomic_store(p, ((u64)tag << 32) | (u64)b, __ATOMIC_RELAXED, __HIP_MEMORY_SCOPE_AGENT);
}
__device__ __forceinline__ float pollT1(const u64* p, u32 tag){
  u64* q = const_cast<u64*>(p);
  u64 w = __hip_atomic_load(q, __ATOMIC_RELAXED, __HIP_MEMORY_SCOPE_AGENT);
  u32 guard = 0;
  while ((u32)(w >> 32) != tag){
    if ((guard & 63u) == 63u && abort_now()) break;
    if (++guard > (1u<<16)){ raise_abort(); break; }
    __builtin_amdgcn_s_sleep(1);
    w = __hip_atomic_load(q, __ATOMIC_RELAXED, __HIP_MEMORY_SCOPE_AGENT);
  }
  u32 b = (u32)w; float v; __builtin_memcpy(&v, &b, 4); return v;
}
template<int NW, int CNT>
__device__ __forceinline__ void pollW(const u64* src, u32 tag, float* dst){
  const int tid = threadIdx.x;
  u64* s = const_cast<u64*>(src);
  u64 w[NW];
  #pragma unroll
  for (int r = 0; r < NW; ++r){
    const int i = tid + BLK*r;
    w[r] = (i < CNT) ? __hip_atomic_load(s + i, __ATOMIC_RELAXED, __HIP_MEMORY_SCOPE_AGENT)
                     : ((u64)tag << 32);
  }
  u32 guard = 0;
  for (;;){
    bool all = true;
    #pragma unroll
    for (int r = 0; r < NW; ++r) if ((u32)(w[r] >> 32) != tag) all = false;
    if (all) break;
    if ((guard & 63u) == 63u && abort_now()) break;
    if (++guard > (1u<<16)){ raise_abort(); break; }
    __builtin_amdgcn_s_sleep(1);
    #pragma unroll
    for (int r = 0; r < NW; ++r){
      const int i = tid + BLK*r;
      if (i < CNT && (u32)(w[r] >> 32) != tag)
        w[r] = __hip_atomic_load(s + i, __ATOMIC_RELAXED, __HIP_MEMORY_SCOPE_AGENT);
    }
  }
  #pragma unroll
  for (int r = 0; r < NW; ++r){
    const int i = tid + BLK*r;
    if (i < CNT){ u32 b = (u32)w[r]; float v; __builtin_memcpy(&v, &b, 4); dst[i] = v; }
  }
}

__device__ __forceinline__ float softplus_f(float x){
  return fmaxf(x, 0.0f) + log1pf(expf(-fabsf(x)));
}

__global__ __launch_bounds__(BLK)
void ode_kernel(const float* __restrict__ y0p,
                const float* __restrict__ Win,  const float* __restrict__ bin,
                const float* __restrict__ Whid, const float* __restrict__ bhid,
                const float* __restrict__ Wout, const float* __restrict__ bout,
                const float* __restrict__ eps,  float* __restrict__ out)
{
  __shared__ float h4s[8][HID];      // retained h4 per slot (1..7); [0..3] = y0 scratch at init
  __shared__ float hshA[HID], hshB[HID];
  __shared__ float hBs[HID], hEs[HID];
  __shared__ float us[8][16];
  __shared__ float vsl[16], b1s[16];
  __shared__ float ysl[64], y1sl[64], esl[64];
  __shared__ float red0;
  __shared__ int s_ab;

  const int tid  = threadIdx.x, blk = blockIdx.x;
  const int wave = tid >> 6, lane = tid & 63;
  const int hl = lane >> 5, lane32 = lane & 31;
  const int hrow = blk*16 + wave*2 + hl;            // hidden/M row (2 per wave, 16 per block)
  const int ro = tid >> 3, l8 = tid & 7;            // out-slot 0..63, 8 lanes/row
  const int orow = (ro >> 4)*HID + blk*16 + (ro & 15);
  const int gi   = (tid >> 4)*HID + blk*16 + (tid & 15);   // owned y index (tid<64)

  // ---- preload hidden + M weight rows into registers (loop-invariant) ----
  float4 wr0[6], wr1[6], wr2[6], mreg[6];
  {
    const float4* b0 = reinterpret_cast<const float4*>(Whid + ((size_t)0*HID + hrow)*HID) + lane32;
    const float4* b1 = reinterpret_cast<const float4*>(Whid + ((size_t)1*HID + hrow)*HID) + lane32;
    const float4* b2 = reinterpret_cast<const float4*>(Whid + ((size_t)2*HID + hrow)*HID) + lane32;
    const float4* mb = reinterpret_cast<const float4*>(g_M  + (size_t)hrow*HID) + lane32;
    #pragma unroll
    for (int i = 0; i < 6; ++i){
      wr0[i] = b0[32*i]; wr1[i] = b1[32*i]; wr2[i] = b2[32*i]; mreg[i] = mb[32*i];
    }
  }
  const float4* wo4 = reinterpret_cast<const float4*>(Wout + (size_t)orow*HID) + l8;
  const float bh0 = bhid[hrow], bh1v = bhid[HID+hrow], bh2v = bhid[2*HID+hrow];
  const float c0r = g_c0[hrow];
  const float bo_r = bout[orow];

  // ---- init ----
  if (tid < 64) ysl[tid] = y0p[gi];
  if (tid < 16) b1s[tid] = bin[blk*16 + tid];
  if (tid < 16){ const int e = blk*16 + tid; out[e] = y0p[e] + eps[e]*y0p[HID+e]; }
  {
    float* scratch = &h4s[0][0];
    float4* d4 = reinterpret_cast<float4*>(scratch);
    const float4* s4 = reinterpret_cast<const float4*>(y0p);
    d4[tid] = s4[tid];
    if (tid < NSTATE/4 - BLK) d4[tid + BLK] = s4[tid + BLK];
    __syncthreads();
    const int vrow = blk*16 + (tid >> 5);
    const int v32 = tid & 31;
    const float4* wr = reinterpret_cast<const float4*>(Win + (size_t)vrow*NSTATE) + v32;
    const float4* zl = reinterpret_cast<const float4*>(scratch) + v32;
    float acc = 0.f;
    #pragma unroll
    for (int i = 0; i < 24; ++i){
      float4 w = wr[32*i], x = zl[32*i];
      acc = fmaf(w.x,x.x, fmaf(w.y,x.y, fmaf(w.z,x.z, fmaf(w.w,x.w, acc))));
    }
    acc += __shfl_xor(acc,16); acc += __shfl_xor(acc,8);
    acc += __shfl_xor(acc,4);  acc += __shfl_xor(acc,2);  acc += __shfl_xor(acc,1);
    if (v32 == 0) vsl[tid >> 5] = acc;           // v = Win·y (no bias)
    __syncthreads();
  }

  u32 hseq = 0, pseq = 0;
  int kpar = 0;
  auto slot = [&](int j){ return (j==1) ? (kpar?7:1) : (j==7) ? (kpar?1:7) : j; };

  auto stage = [&](int s, float dte){
    __syncthreads();
    const int tg = slot(s + 1);
    ++hseq;
    if (tid < 16){
      float a = 0.f;
      for (int j = 1; j <= s; ++j) a += d_AT[s][j-1] * us[slot(j)][tid];
      stT(&gt.h[hseq&1][blk*16 + tid], hseq, softplus_f(vsl[tid] + dte*a + b1s[tid]));
    }
    pollW<2, HID>(gt.h[hseq&1], hseq, hshA);
    __syncthreads();
    #pragma unroll
    for (int l = 0; l < 3; ++l){
      const float* rbuf = (l == 1) ? hshB : hshA;         // A, B, A
      const float4* hx = reinterpret_cast<const float4*>(rbuf) + lane32;
      float acc = 0.f;
      #pragma unroll
      for (int i = 0; i < 6; ++i){
        float4 w = (l==0) ? wr0[i] : (l==1) ? wr1[i] : wr2[i];
        float4 x = hx[32*i];
        acc = fmaf(w.x,x.x, fmaf(w.y,x.y, fmaf(w.z,x.z, fmaf(w.w,x.w, acc))));
      }
      acc += __shfl_xor(acc,16); acc += __shfl_xor(acc,8);
      acc += __shfl_xor(acc,4);  acc += __shfl_xor(acc,2);  acc += __shfl_xor(acc,1);
      const float bh = (l==0) ? bh0 : (l==1) ? bh1v : bh2v;
      ++hseq;
      if (lane32 == 0) stT(&gt.h[hseq&1][hrow], hseq, softplus_f(acc + bh));
      // double-buffer: poll writes the buffer nobody is reading
      pollW<2, HID>(gt.h[hseq&1], hseq, (l==0) ? hshB : (l==1) ? hshA : h4s[tg]);
      __syncthreads();
    }
    // u_{s+1} = M·h4 + c0 (owner-local, M in registers)
    {
      const float4* hx = reinterpret_cast<const float4*>(h4s[tg]) + lane32;
      float acc = 0.f;
      #pragma unroll
      for (int i = 0; i < 6; ++i){
        float4 w = mreg[i], x = hx[32*i];
        acc = fmaf(w.x,x.x, fmaf(w.y,x.y, fmaf(w.z,x.z, fmaf(w.w,x.w, acc))));
      }
      acc += __shfl_xor(acc,16); acc += __shfl_xor(acc,8);
      acc += __shfl_xor(acc,4);  acc += __shfl_xor(acc,2);  acc += __shfl_xor(acc,1);
      if (lane32 == 0) us[tg][wave*2 + hl] = acc + c0r;
    }
  };

  // k1 = f(y0) once; FSAL-carried afterwards
  stage(0, 0.f);

  float t = 0.f, dtv = 0.1f;
  for (int iv = 1; iv < 100; ++iv){
    const float t1 = (float)iv / 99.0f;
    for (int a = 0; a < 6; ++a){
      if (t >= t1 - 1e-10f) break;
      if (tid == 0) s_ab = abort_now();
      __syncthreads();
      if (s_ab) return;                        // fail fast, never wedge
      const float dte = fminf(dtv, t1 - t);

      stage(1,dte); stage(2,dte); stage(3,dte);
      stage(4,dte); stage(5,dte); stage(6,dte);
      __syncthreads();

      // hB = Σ B_j h4_j ; hE = Σ E_j h4_j (elementwise, local)
      for (int c = tid; c < HID; c += BLK){
        float hb = 0.f, he = 0.f;
        for (int j = 1; j <= 6; ++j) hb = fmaf(d_AT[6][j-1], h4s[slot(j)][c], hb);
        for (int j = 1; j <= 7; ++j) he = fmaf(d_EC[j-1],    h4s[slot(j)][c], he);
        hBs[c] = hb; hEs[c] = he;
      }
      __syncthreads();
      // y1, e on owned out-rows (8 lanes/row)
      {
        const float4* hb4 = reinterpret_cast<const float4*>(hBs) + l8;
        const float4* he4 = reinterpret_cast<const float4*>(hEs) + l8;
        float ab = 0.f, ae = 0.f;
        #pragma unroll
        for (int i = 0; i < 24; ++i){
          float4 w = wo4[8*i], xb = hb4[8*i], xe = he4[8*i];
          ab = fmaf(w.x,xb.x, fmaf(w.y,xb.y, fmaf(w.z,xb.z, fmaf(w.w,xb.w, ab))));
          ae = fmaf(w.x,xe.x, fmaf(w.y,xe.y, fmaf(w.z,xe.z, fmaf(w.w,xe.w, ae))));
        }
        ab += __shfl_xor(ab,4); ab += __shfl_xor(ab,2); ab += __shfl_xor(ab,1);
        ae += __shfl_xor(ae,4); ae += __shfl_xor(ae,2); ae += __shfl_xor(ae,1);
        if (l8 == 0){
          y1sl[ro] = ysl[ro] + dte*(ab + SBc*bo_r);
          esl[ro]  = dte*(ae + SEc*bo_r);
        }
      }
      __syncthreads();
      // err partial over owned 64 elements (wave 0) -> publish
      ++pseq;
      if (tid < 64){
        const float sc = 1e-6f + 1e-3f * fmaxf(fabsf(ysl[tid]), fabsf(y1sl[tid]));
        const float q = esl[tid] / sc;
        float v = q*q;
        v += __shfl_xor(v,32); v += __shfl_xor(v,16); v += __shfl_xor(v,8);
        v += __shfl_xor(v,4);  v += __shfl_xor(v,2);  v += __shfl_xor(v,1);
        if (tid == 0) stT(&gt.p[pseq&1][blk], pseq, v);
      }
      // gather 48 partials (wave 0), deterministic fixed-order reduce
      {
        float v = 0.f;
        if (tid < NBLK) v = pollT1(&gt.p[pseq&1][tid], pseq);
        if (wave == 0){
          v += __shfl_xor(v,32); v += __shfl_xor(v,16); v += __shfl_xor(v,8);
          v += __shfl_xor(v,4);  v += __shfl_xor(v,2);  v += __shfl_xor(v,1);
          if (tid == 0) red0 = v;
        }
      }
      __syncthreads();
      const float err = sqrtf(red0 * (1.0f/3072.0f));
      __syncthreads();

      const bool accept = (err <= 1.0f);
      const float factor = fminf(fmaxf(0.9f * powf(fmaxf(err, 1e-10f), -0.2f), 0.2f), 10.0f);
      if (accept){
        t += dte;
        if (tid < 64) ysl[tid] = y1sl[tid];
        if (tid < 16){
          float s = 0.f;
          for (int j = 1; j <= 6; ++j) s += d_AT[6][j-1] * us[slot(j)][tid];
          vsl[tid] += dte * s;                 // v = Win·y1 exactly (u-algebra)
        }
        kpar ^= 1;                             // k1 <- k7 (u & h4 slot swap)
      }
      dtv = dte * factor;
      __syncthreads();
    }
    t = t1;
    // output emission: block-local thanks to permuted W_out ownership
    if (tid < 16){
      const int m = blk*16 + tid;
      out[(size_t)iv*HID + m] = ysl[tid] + eps[(size_t)iv*HID + m] * ysl[16 + tid];
    }
    __syncthreads();
  }
}

extern "C" void kernel_launch(void* const* d_in, const int* in_sizes, int n_in,
                              void* d_out, int out_size, void* d_ws, size_t ws_size,
                              hipStream_t stream) {
  const float* y0   = (const float*)d_in[0];
  const float* Win  = (const float*)d_in[1];
  const float* bin  = (const float*)d_in[2];
  const float* Whid = (const float*)d_in[3];
  const float* bhid = (const float*)d_in[4];
  const float* Wout = (const float*)d_in[5];
  const float* bout = (const float*)d_in[6];
  const float* eps  = (const float*)d_in[7];
  float* out = (float*)d_out;
  (void)in_sizes; (void)n_in; (void)out_size; (void)d_ws; (void)ws_size;

  const int prep_lds = 8 * NSTATE * 4;   // 96 KB
  (void)hipFuncSetAttribute(reinterpret_cast<const void*>(&prep_kernel),
                            hipFuncAttributeMaxDynamicSharedMemorySize, prep_lds);
  reset_kernel<<<dim3(4), dim3(BLK), 0, stream>>>();
  prep_kernel<<<dim3(96), dim3(512), prep_lds, stream>>>(Win, Wout, bout);
  ode_kernel<<<dim3(NBLK), dim3(BLK), 0, stream>>>(y0, Win, bin, Whid, bhid, Wout, bout, eps, out);
}